// Round 4
// baseline (333.558 us; speedup 1.0000x reference)
//
#include <hip/hip_runtime.h>

#define N_NODES 100000
#define DEG 16
#define DIM 128
#define NGROUPS 6250        // N_NODES / 16
#define GPB 5               // node-groups per dense block
#define DBLOCKS (NGROUPS / GPB)   // 1250

typedef short bf16x8 __attribute__((ext_vector_type(8)));
typedef float f32x4 __attribute__((ext_vector_type(4)));

__device__ __forceinline__ unsigned short f2bf(float f) {
    unsigned int u = __builtin_bit_cast(unsigned int, f);
    u = (u + 0x7fffu + ((u >> 16) & 1u)) >> 16;
    return (unsigned short)u;
}
__device__ __forceinline__ float bf2f(unsigned short h) {
    unsigned int u = ((unsigned int)h) << 16;
    return __builtin_bit_cast(float, u);
}

// ---------------------------------------------------------------------------
// dense_fused: zcat[n][0:128] = h @ W_W^T, zcat[n][128:256] = h @ W_U^T (bf16)
// plus fused s_src[n] = z.a_src, s_dst[n] = z.a_dst.
// Operand-swapped MFMA: A = W rows (m = output col), B = h rows (n = node).
// C/D: n = lane&15 (node), m = quad*4 + r (4 consecutive output cols/lane).
// Wave w owns output cols [w*64, w*64+64). Loops GPB node-groups.
// F32IN: h is fp32 (layer 1, reads attr directly); else bf16 (h1).
// ---------------------------------------------------------------------------
template <bool F32IN>
__global__ __launch_bounds__(256) void dense_fused(
    const void* __restrict__ hsrc,           // N x 128 (f32 or bf16)
    const float* __restrict__ W_W,           // 128 x 128 f32
    const float* __restrict__ W_U,           // 128 x 128 f32
    const float* __restrict__ W_a,           // 257 f32
    unsigned short* __restrict__ zcat,       // N x 256 bf16
    float* __restrict__ s_src,
    float* __restrict__ s_dst)
{
    __shared__ float sred[2][2][2][16];      // [g&1][wave<2][ss/sd][node16]

    const int wave = threadIdx.x >> 6;
    const int lane = threadIdx.x & 63;
    const int n16 = lane & 15;
    const int quad = lane >> 4;

    // A-operand: W rows = output cols [wave*64 .. wave*64+64)
    const float* Wbase = (wave < 2) ? (W_W + (size_t)wave * 64 * DIM)
                                    : (W_U + (size_t)(wave - 2) * 64 * DIM);
    bf16x8 wfrag[4][4];                      // [ct][ks]
#pragma unroll
    for (int ct = 0; ct < 4; ct++) {
        const float* wrow = Wbase + (size_t)(ct * 16 + n16) * DIM + quad * 8;
#pragma unroll
        for (int ks = 0; ks < 4; ks++) {
            float4 lo = *(const float4*)(wrow + ks * 32);
            float4 hi = *(const float4*)(wrow + ks * 32 + 4);
            bf16x8 f;
            f[0] = (short)f2bf(lo.x); f[1] = (short)f2bf(lo.y);
            f[2] = (short)f2bf(lo.z); f[3] = (short)f2bf(lo.w);
            f[4] = (short)f2bf(hi.x); f[5] = (short)f2bf(hi.y);
            f[6] = (short)f2bf(hi.z); f[7] = (short)f2bf(hi.w);
            wfrag[ct][ks] = f;
        }
    }

    // fused-score vectors (waves 0,1 hold z cols 0..127)
    float4 av_s[4], av_d[4];
    if (wave < 2) {
#pragma unroll
        for (int ct = 0; ct < 4; ct++) {
            av_s[ct] = *(const float4*)(W_a + wave * 64 + ct * 16 + quad * 4);
            av_d[ct] = *(const float4*)(W_a + DIM + wave * 64 + ct * 16 + quad * 4);
        }
    }

    for (int g = 0; g < GPB; g++) {
        const int nodebase = (blockIdx.x * GPB + g) * 16;

        // B-operand: 16 h rows
        bf16x8 hfrag[4];
        if (F32IN) {
            const float* hrow = (const float*)hsrc + (size_t)(nodebase + n16) * DIM + quad * 8;
#pragma unroll
            for (int ks = 0; ks < 4; ks++) {
                float4 lo = *(const float4*)(hrow + ks * 32);
                float4 hi = *(const float4*)(hrow + ks * 32 + 4);
                bf16x8 f;
                f[0] = (short)f2bf(lo.x); f[1] = (short)f2bf(lo.y);
                f[2] = (short)f2bf(lo.z); f[3] = (short)f2bf(lo.w);
                f[4] = (short)f2bf(hi.x); f[5] = (short)f2bf(hi.y);
                f[6] = (short)f2bf(hi.z); f[7] = (short)f2bf(hi.w);
                hfrag[ks] = f;
            }
        } else {
            const unsigned short* hrow = (const unsigned short*)hsrc + (size_t)(nodebase + n16) * DIM + quad * 8;
#pragma unroll
            for (int ks = 0; ks < 4; ks++)
                hfrag[ks] = *(const bf16x8*)(hrow + ks * 32);
        }

        f32x4 acc[4];
#pragma unroll
        for (int ct = 0; ct < 4; ct++) {
            f32x4 a = {0.f, 0.f, 0.f, 0.f};
#pragma unroll
            for (int ks = 0; ks < 4; ks++)
                a = __builtin_amdgcn_mfma_f32_16x16x32_bf16(wfrag[ct][ks], hfrag[ks], a, 0, 0, 0);
            acc[ct] = a;
        }

        // store: node = nodebase+n16, cols wave*64 + ct*16 + quad*4 + (0..3)
        unsigned short* orow = zcat + (size_t)(nodebase + n16) * 256 + wave * 64 + quad * 4;
#pragma unroll
        for (int ct = 0; ct < 4; ct++) {
            uint2 pk;
            pk.x = (unsigned int)f2bf(acc[ct][0]) | ((unsigned int)f2bf(acc[ct][1]) << 16);
            pk.y = (unsigned int)f2bf(acc[ct][2]) | ((unsigned int)f2bf(acc[ct][3]) << 16);
            *(uint2*)(orow + ct * 16) = pk;
        }

        // fused scores (z cols only -> waves 0,1)
        if (wave < 2) {
            float ps = 0.f, pd = 0.f;
#pragma unroll
            for (int ct = 0; ct < 4; ct++) {
                ps += acc[ct][0] * av_s[ct].x + acc[ct][1] * av_s[ct].y
                    + acc[ct][2] * av_s[ct].z + acc[ct][3] * av_s[ct].w;
                pd += acc[ct][0] * av_d[ct].x + acc[ct][1] * av_d[ct].y
                    + acc[ct][2] * av_d[ct].z + acc[ct][3] * av_d[ct].w;
            }
            ps += __shfl_xor(ps, 16); ps += __shfl_xor(ps, 32);
            pd += __shfl_xor(pd, 16); pd += __shfl_xor(pd, 32);
            if (lane < 16) {
                sred[g & 1][wave][0][n16] = ps;
                sred[g & 1][wave][1][n16] = pd;
            }
        }
        __syncthreads();
        if (wave == 3) {
            if (lane < 16)
                s_src[nodebase + lane] = sred[g & 1][0][0][lane] + sred[g & 1][1][0][lane];
            else if (lane < 32)
                s_dst[nodebase + lane - 16] = sred[g & 1][0][1][lane - 16] + sred[g & 1][1][1][lane - 16];
        }
        // next iter uses the other sred parity buffer; its barrier orders reuse
    }
}

// ---------------------------------------------------------------------------
// aggr v3: 16 nodes/block, 256 threads.
// Phase 1: exactly 1 thread/edge (256 edges), 16-lane shfl softmax -> LDS.
// Phase 2: 16 threads/node, 8 cols each, uint4 (16 B) bf16 gathers.
// ---------------------------------------------------------------------------
__global__ __launch_bounds__(256) void aggr_kernel(
    const unsigned short* __restrict__ zcat,
    const float* __restrict__ s_src,
    const float* __restrict__ s_dst,
    const float* __restrict__ edge_d,
    const int* __restrict__ edge_src,
    const float* __restrict__ W_V,          // 1 float
    const float* __restrict__ W_a,          // a_t = W_a[256]
    unsigned short* __restrict__ out_bf16,  // layer-1 target (or null)
    float* __restrict__ out_f32)            // layer-2 target (or null)
{
    __shared__ float alpha_s[16][DEG];
    __shared__ int   src_s[16][DEG];

    const int t = threadIdx.x;
    const int base = blockIdx.x * 16;

    // ---- phase 1: one thread per edge ----
    {
        int nl = t >> 4, j = t & 15;
        int node = base + nl;
        int e = node * DEG + j;
        int s = edge_src[e];
        float coef = W_V[0] * W_a[2 * DIM];
        float x = s_src[s] + s_dst[node] + edge_d[e] * coef;
        x = x > 0.f ? x : 0.01f * x;
        float m = x;
        m = fmaxf(m, __shfl_xor(m, 1));
        m = fmaxf(m, __shfl_xor(m, 2));
        m = fmaxf(m, __shfl_xor(m, 4));
        m = fmaxf(m, __shfl_xor(m, 8));
        float ex = __expf(x - m);
        float d = ex;
        d += __shfl_xor(d, 1); d += __shfl_xor(d, 2);
        d += __shfl_xor(d, 4); d += __shfl_xor(d, 8);
        alpha_s[nl][j] = ex / d;
        src_s[nl][j] = s;
    }
    __syncthreads();

    // ---- phase 2: 16 threads/node, 8 cols each ----
    const int nl = t >> 4;
    const int node = base + nl;
    const int c8 = (t & 15) * 8;

    float acc[8] = {};
#pragma unroll
    for (int j = 0; j < DEG; j++) {
        int s = src_s[nl][j];           // LDS broadcast
        float a = alpha_s[nl][j];       // LDS broadcast
        uint4 raw = *(const uint4*)(zcat + (size_t)s * 256 + c8);
        acc[0] += a * bf2f((unsigned short)raw.x);
        acc[1] += a * bf2f((unsigned short)(raw.x >> 16));
        acc[2] += a * bf2f((unsigned short)raw.y);
        acc[3] += a * bf2f((unsigned short)(raw.y >> 16));
        acc[4] += a * bf2f((unsigned short)raw.z);
        acc[5] += a * bf2f((unsigned short)(raw.z >> 16));
        acc[6] += a * bf2f((unsigned short)raw.w);
        acc[7] += a * bf2f((unsigned short)(raw.w >> 16));
    }

    uint4 zr = *(const uint4*)(zcat + (size_t)node * 256 + 128 + c8);
    float v[8];
    v[0] = fmaxf(bf2f((unsigned short)zr.x) + acc[0], 0.f);
    v[1] = fmaxf(bf2f((unsigned short)(zr.x >> 16)) + acc[1], 0.f);
    v[2] = fmaxf(bf2f((unsigned short)zr.y) + acc[2], 0.f);
    v[3] = fmaxf(bf2f((unsigned short)(zr.y >> 16)) + acc[3], 0.f);
    v[4] = fmaxf(bf2f((unsigned short)zr.z) + acc[4], 0.f);
    v[5] = fmaxf(bf2f((unsigned short)(zr.z >> 16)) + acc[5], 0.f);
    v[6] = fmaxf(bf2f((unsigned short)zr.w) + acc[6], 0.f);
    v[7] = fmaxf(bf2f((unsigned short)(zr.w >> 16)) + acc[7], 0.f);

    if (out_f32) {
        float* op = out_f32 + (size_t)node * DIM + c8;
        *(float4*)op       = make_float4(v[0], v[1], v[2], v[3]);
        *(float4*)(op + 4) = make_float4(v[4], v[5], v[6], v[7]);
    } else {
        uint4 pk;
        pk.x = (unsigned int)f2bf(v[0]) | ((unsigned int)f2bf(v[1]) << 16);
        pk.y = (unsigned int)f2bf(v[2]) | ((unsigned int)f2bf(v[3]) << 16);
        pk.z = (unsigned int)f2bf(v[4]) | ((unsigned int)f2bf(v[5]) << 16);
        pk.w = (unsigned int)f2bf(v[6]) | ((unsigned int)f2bf(v[7]) << 16);
        *(uint4*)(out_bf16 + (size_t)node * DIM + c8) = pk;
    }
}

// ---------------------------------------------------------------------------
extern "C" void kernel_launch(void* const* d_in, const int* in_sizes, int n_in,
                              void* d_out, int out_size, void* d_ws, size_t ws_size,
                              hipStream_t stream) {
    const float* attr     = (const float*)d_in[0];
    const float* edge_d   = (const float*)d_in[1];
    const float* W_V1     = (const float*)d_in[2];
    const float* W_W1     = (const float*)d_in[3];
    const float* W_U1     = (const float*)d_in[4];
    const float* W_a1     = (const float*)d_in[5];
    const float* W_V2     = (const float*)d_in[6];
    const float* W_W2     = (const float*)d_in[7];
    const float* W_U2     = (const float*)d_in[8];
    const float* W_a2     = (const float*)d_in[9];
    const int*   edge_src = (const int*)d_in[10];

    float* out = (float*)d_out;

    char* ws = (char*)d_ws;
    unsigned short* zcat = (unsigned short*)ws;                        // 51.2 MB
    unsigned short* h1   = (unsigned short*)(ws + 52u * 1024 * 1024);  // 25.6 MB
    float* s_src         = (float*)(ws + 78u * 1024 * 1024);           // 400 KB
    float* s_dst         = (float*)(ws + 79u * 1024 * 1024);           // 400 KB

    // ---- layer 1 ----
    dense_fused<true><<<DBLOCKS, 256, 0, stream>>>(attr, W_W1, W_U1, W_a1,
                                                   zcat, s_src, s_dst);
    aggr_kernel<<<NGROUPS, 256, 0, stream>>>(zcat, s_src, s_dst, edge_d, edge_src,
                                             W_V1, W_a1, h1, nullptr);

    // ---- layer 2 ----
    dense_fused<false><<<DBLOCKS, 256, 0, stream>>>(h1, W_W2, W_U2, W_a2,
                                                    zcat, s_src, s_dst);
    aggr_kernel<<<NGROUPS, 256, 0, stream>>>(zcat, s_src, s_dst, edge_d, edge_src,
                                             W_V2, W_a2, nullptr, out);
}